// Round 1
// baseline (463.387 us; speedup 1.0000x reference)
//
#include <hip/hip_runtime.h>

#define BSZ 32
#define SLEN 512
#define CLEN 20
#define DMOD 256
#define NH 4
#define HDIM 64

// ---------------- embedding sum + positional encoding ----------------
__global__ __launch_bounds__(256) void k_embed(
    const int* __restrict__ seqs, const int* __restrict__ lengths,
    const float* __restrict__ emb, const float* __restrict__ bias,
    const float* __restrict__ pe, float* __restrict__ x) {
  const int row = blockIdx.x;            // b*SLEN + s
  const int b = row >> 9, s = row & 511;
  const int d = threadIdx.x;
  __shared__ int codes[CLEN];
  if (threadIdx.x < CLEN) codes[threadIdx.x] = seqs[row * CLEN + threadIdx.x];
  __syncthreads();
  const int pos = (s < lengths[b]) ? (s + 1) : 0;
  float acc = bias[d] + pe[pos * DMOD + d];
  #pragma unroll
  for (int c = 0; c < CLEN; ++c)
    acc += emb[(size_t)codes[c] * DMOD + d];
  x[(size_t)row * DMOD + d] = acc;
}

// ---------------- C = A @ W^T (+res), A:[M,256], W:[256,256] ----------------
#define BM 64
#define BN 64
#define BK 32

__global__ __launch_bounds__(256, 4) void k_gemm(
    const float* __restrict__ A,
    const float* __restrict__ W0, const float* __restrict__ W1, const float* __restrict__ W2,
    float* __restrict__ C0, float* __restrict__ C1, float* __restrict__ C2,
    const float* __restrict__ res, int use_res) {
  const float* W; float* C;
  if (blockIdx.z == 0)      { W = W0; C = C0; }
  else if (blockIdx.z == 1) { W = W1; C = C1; }
  else                      { W = W2; C = C2; }
  const int m0 = blockIdx.x * BM;
  const int n0 = blockIdx.y * BN;
  const int tid = threadIdx.x;
  __shared__ float As[BK][BM + 4];   // [k][m], stride 68 keeps float4 reads 16B-aligned
  __shared__ float Ws[BK][BN + 4];   // [k][n]
  float acc[4][4] = {};
  const int tm = (tid & 15) * 4;
  const int tn = (tid >> 4) * 4;
  for (int k0 = 0; k0 < DMOD; k0 += BK) {
    #pragma unroll
    for (int i = 0; i < 2; ++i) {
      const int lin = tid + i * 256;
      const int r = lin >> 3;
      const int c4 = (lin & 7) * 4;
      const float4 av = *(const float4*)(A + (size_t)(m0 + r) * DMOD + k0 + c4);
      As[c4 + 0][r] = av.x; As[c4 + 1][r] = av.y; As[c4 + 2][r] = av.z; As[c4 + 3][r] = av.w;
      const float4 wv = *(const float4*)(W + (size_t)(n0 + r) * DMOD + k0 + c4);
      Ws[c4 + 0][r] = wv.x; Ws[c4 + 1][r] = wv.y; Ws[c4 + 2][r] = wv.z; Ws[c4 + 3][r] = wv.w;
    }
    __syncthreads();
    #pragma unroll
    for (int k = 0; k < BK; ++k) {
      float a[4], w[4];
      *(float4*)a = *(const float4*)&As[k][tm];
      *(float4*)w = *(const float4*)&Ws[k][tn];
      #pragma unroll
      for (int i = 0; i < 4; ++i)
        #pragma unroll
        for (int j = 0; j < 4; ++j)
          acc[i][j] += a[i] * w[j];
    }
    __syncthreads();
  }
  #pragma unroll
  for (int i = 0; i < 4; ++i) {
    float outv[4];
    if (use_res) {
      float r4[4];
      *(float4*)r4 = *(const float4*)(res + (size_t)(m0 + tm + i) * DMOD + n0 + tn);
      #pragma unroll
      for (int j = 0; j < 4; ++j) outv[j] = acc[i][j] + r4[j];
    } else {
      #pragma unroll
      for (int j = 0; j < 4; ++j) outv[j] = acc[i][j];
    }
    *(float4*)(C + (size_t)(m0 + tm + i) * DMOD + n0 + tn) = *(float4*)outv;
  }
}

// ---------------- fused attention per (b,h,q-tile of 64) ----------------
// Q/K/V views: contiguous [512,64] blocks at (b*4+h)*512*64 (faithful reshape).
// softmax computed as exp(e)/sum(exp(e)) (no max-sub; |e| small, math-identical).
__global__ __launch_bounds__(256, 2) void k_attn(
    const float* __restrict__ Q, const float* __restrict__ K, const float* __restrict__ V,
    const int* __restrict__ masks, float* __restrict__ O) {
  const int bh = blockIdx.y;
  const int b = bh >> 2, h = bh & 3;
  const int q0 = blockIdx.x * 64;
  const float* Qb = Q + (size_t)bh * SLEN * HDIM;
  const float* Kb = K + (size_t)bh * SLEN * HDIM;
  const float* Vb = V + (size_t)bh * SLEN * HDIM;
  const int* mb = masks + (size_t)b * SLEN * SLEN;
  __shared__ float Qs[HDIM][64 + 4];   // transposed [d][q]
  __shared__ float Ks[HDIM][64 + 4];   // transposed [d][k]
  __shared__ float Vs[64][HDIM + 4];   // natural   [k][d]
  __shared__ float Es[64][64 + 4];     // exp(e)    [k][q]
  __shared__ float lsum[64];
  const int tid = threadIdx.x;
  const int qg = (tid & 15) * 4;       // q sub-tile base (phase i & ii)
  const int kg = (tid >> 4) * 4;       // k sub-tile base (phase i) == d base (phase ii)
  {
    const int d = tid & 63;
    const int qb = tid >> 6;
    #pragma unroll
    for (int p = 0; p < 16; ++p) {
      const int qq = qb + p * 4;
      Qs[d][qq] = Qb[(size_t)(q0 + qq) * HDIM + d];
    }
  }
  if (tid < 64) lsum[tid] = 0.f;
  __syncthreads();
  float oacc[4][4] = {};
  for (int kc = 0; kc < SLEN; kc += 64) {
    {
      const int d = tid & 63;
      const int kb = tid >> 6;
      #pragma unroll
      for (int p = 0; p < 16; ++p) {
        const int kk = kb + p * 4;
        Ks[d][kk] = Kb[(size_t)(kc + kk) * HDIM + d];
      }
      #pragma unroll
      for (int p = 0; p < 4; ++p) {
        const int lin = tid + p * 256;
        const int kk = lin >> 4;
        const int d4 = (lin & 15) * 4;
        *(float4*)&Vs[kk][d4] = *(const float4*)(Vb + (size_t)(kc + kk) * HDIM + d4);
      }
    }
    __syncthreads();
    // phase i: e[4q][4k] = sum_d q*k
    float e[4][4] = {};
    #pragma unroll 8
    for (int d = 0; d < HDIM; ++d) {
      float aq[4], ak[4];
      *(float4*)aq = *(const float4*)&Qs[d][qg];
      *(float4*)ak = *(const float4*)&Ks[d][kg];
      #pragma unroll
      for (int i = 0; i < 4; ++i)
        #pragma unroll
        for (int j = 0; j < 4; ++j)
          e[i][j] += aq[i] * ak[j];
    }
    #pragma unroll
    for (int j = 0; j < 4; ++j)
      #pragma unroll
      for (int i = 0; i < 4; ++i) {
        const int mrow = q0 + qg + i;
        const int mcol = kc + kg + j;
        const float ex = (mb[(size_t)mrow * SLEN + mcol] == 0)
                             ? 0.f : __expf(e[i][j] * 0.125f);
        Es[kg + j][qg + i] = ex;
      }
    __syncthreads();
    // row sums of exp(e)
    if (tid < 64) {
      float sacc = 0.f;
      #pragma unroll
      for (int kk = 0; kk < 64; ++kk) sacc += Es[kk][tid];
      lsum[tid] += sacc;
    }
    // phase ii: O[4q][4d] += E^T @ V over this k-chunk
    #pragma unroll 8
    for (int kk = 0; kk < 64; ++kk) {
      float ee[4], vv[4];
      *(float4*)ee = *(const float4*)&Es[kk][qg];
      *(float4*)vv = *(const float4*)&Vs[kk][kg];
      #pragma unroll
      for (int i = 0; i < 4; ++i)
        #pragma unroll
        for (int j = 0; j < 4; ++j)
          oacc[i][j] += ee[i] * vv[j];
    }
    __syncthreads();
  }
  // normalize + write in final transposed layout: O[b, s, h*64 + d]
  #pragma unroll
  for (int i = 0; i < 4; ++i) {
    const float inv = 1.0f / lsum[qg + i];
    float ov[4];
    #pragma unroll
    for (int j = 0; j < 4; ++j) ov[j] = oacc[i][j] * inv;
    *(float4*)(O + ((size_t)(b * SLEN + q0 + qg + i)) * DMOD + h * HDIM + kg) = *(float4*)ov;
  }
}

// ---------------- layer norm + zero invalid rows (in-place safe) ----------------
__global__ __launch_bounds__(256) void k_ln(
    const float* __restrict__ Y, const int* __restrict__ lengths,
    const float* __restrict__ g, const float* __restrict__ bb,
    float* __restrict__ out) {
  const int row = blockIdx.x * 4 + (threadIdx.x >> 6);
  const int lane = threadIdx.x & 63;
  const int b = row >> 9, s = row & 511;
  const float* yr = Y + (size_t)row * DMOD;
  float v[4];
  *(float4*)v = *(const float4*)(yr + lane * 4);
  float sum = v[0] + v[1] + v[2] + v[3];
  #pragma unroll
  for (int off = 32; off > 0; off >>= 1) sum += __shfl_xor(sum, off);
  const float mu = sum * (1.0f / DMOD);
  float vs = 0.f;
  #pragma unroll
  for (int i = 0; i < 4; ++i) { const float dx = v[i] - mu; vs += dx * dx; }
  #pragma unroll
  for (int off = 32; off > 0; off >>= 1) vs += __shfl_xor(vs, off);
  const float inv = rsqrtf(vs * (1.0f / DMOD) + 1e-5f);
  const bool valid = s < lengths[b];
  float gg[4], bv[4], ov[4];
  *(float4*)gg = *(const float4*)(g + lane * 4);
  *(float4*)bv = *(const float4*)(bb + lane * 4);
  #pragma unroll
  for (int i = 0; i < 4; ++i)
    ov[i] = valid ? ((v[i] - mu) * inv * gg[i] + bv[i]) : 0.f;
  *(float4*)(out + (size_t)row * DMOD + lane * 4) = *(float4*)ov;
}

// ---------------- triangular temporal pooling into 4 bins ----------------
__global__ __launch_bounds__(256) void k_pool(
    const float* __restrict__ X, const int* __restrict__ lengths, float* __restrict__ U) {
  const int m = blockIdx.x;   // bin 0..3
  const int b = blockIdx.y;
  const int d = threadIdx.x;
  const float len = (float)lengths[b];
  const float mm = (float)(m + 1);
  float acc = 0.f;
  for (int s = 0; s < SLEN; ++s) {
    const float sv = 4.0f * (float)(s + 1) / len;
    const float t = 1.0f - fabsf(sv - mm) * 0.25f;
    acc += t * t * X[((size_t)b * SLEN + s) * DMOD + d];
  }
  U[((size_t)b * 4 + m) * DMOD + d] = acc;
}

// ---------------- final [32,1024] @ [1024,2]^T + bias ----------------
__global__ __launch_bounds__(256) void k_out(
    const float* __restrict__ U, const float* __restrict__ ow,
    const float* __restrict__ ob, float* __restrict__ out) {
  const int tid = threadIdx.x;
  const int pair = tid >> 2;       // 0..63 -> (b,i)
  const int part = tid & 3;
  const int b = pair >> 1, i = pair & 1;
  const float4* Ub = (const float4*)(U + (size_t)b * 1024);
  const float4* Wb = (const float4*)(ow + (size_t)i * 1024);
  float acc = 0.f;
  for (int j = part * 64; j < part * 64 + 64; ++j) {
    const float4 u = Ub[j], w = Wb[j];
    acc += u.x * w.x + u.y * w.y + u.z * w.z + u.w * w.w;
  }
  acc += __shfl_xor(acc, 1);
  acc += __shfl_xor(acc, 2);
  if (part == 0) out[b * 2 + i] = acc + ob[i];
}

extern "C" void kernel_launch(void* const* d_in, const int* in_sizes, int n_in,
                              void* d_out, int out_size, void* d_ws, size_t ws_size,
                              hipStream_t stream) {
  const int* seqs     = (const int*)d_in[0];
  const int* masks    = (const int*)d_in[1];
  const int* lengths  = (const int*)d_in[2];
  // d_in[3] seq_time_step, d_in[4] code_masks: unused by the reference
  const float* emb    = (const float*)d_in[5];
  const float* bias   = (const float*)d_in[6];
  const float* pe     = (const float*)d_in[7];
  const float* Wq     = (const float*)d_in[8];
  const float* Wk     = (const float*)d_in[9];
  const float* Wv     = (const float*)d_in[10];
  const float* Wfc    = (const float*)d_in[11];
  const float* ln_g   = (const float*)d_in[12];
  const float* ln_b   = (const float*)d_in[13];
  const float* out_w  = (const float*)d_in[14];
  const float* out_b  = (const float*)d_in[15];
  float* outp = (float*)d_out;

  float* ws = (float*)d_ws;
  const size_t NT = (size_t)BSZ * SLEN;     // 16384 rows
  float* x = ws;                            // embed+pe output (residual)
  float* q = x + NT * DMOD;
  float* k = q + NT * DMOD;
  float* v = k + NT * DMOD;
  float* o = v + NT * DMOD;                 // attention out, final layout
  float* y = o + NT * DMOD;                 // fc + res, then LN in place
  float* U = y + NT * DMOD;                 // [32,4,256]

  k_embed<<<BSZ * SLEN, 256, 0, stream>>>(seqs, lengths, emb, bias, pe, x);
  k_gemm<<<dim3(NT / BM, DMOD / BN, 3), 256, 0, stream>>>(
      x, Wq, Wk, Wv, q, k, v, nullptr, 0);
  k_attn<<<dim3(SLEN / 64, BSZ * NH), 256, 0, stream>>>(q, k, v, masks, o);
  k_gemm<<<dim3(NT / BM, DMOD / BN, 1), 256, 0, stream>>>(
      o, Wfc, Wfc, Wfc, y, y, y, x, 1);
  k_ln<<<NT / 4, 256, 0, stream>>>(y, lengths, ln_g, ln_b, y);
  k_pool<<<dim3(4, BSZ), 256, 0, stream>>>(y, lengths, U);
  k_out<<<1, 256, 0, stream>>>(U, out_w, out_b, outp);
}